// Round 14
// baseline (807.217 us; speedup 1.0000x reference)
//
#include <hip/hip_runtime.h>
#include <hip/hip_fp16.h>

#define N_NODES 100000
#define N_EDGES 3200000
#define BGR 64
#define DIM 16
#define NFP 33
#define ROW1 32
#define H1STR 36
#define EMB 128
#define MAXLEN 3000
#define LOCLEN 2998
#define NF 32
#define KS 8
#define OUTT 121
#define FC_IN 3872
#define BN_EPSV 1e-5f
#define POOL_CHUNK 256
#define POOL_BLKS 391
#define NQUAD 25000
#define AGBLK 2048
#define MLPB 391
// binned CSR build
#define NBIN 391
#define BCNT_BLK 512
#define P1_CHUNK 4096
#define P1_BLOCKS 782
#define MAXBIN 9088
// fc K-split
#define NKC 32
#define KCH 121

// ---------------- CSR build ----------------
__global__ void __launch_bounds__(256) k_bincnt(const int* __restrict__ dst,
                                                int* __restrict__ bh) {
    __shared__ int hist[NBIN];
    int t = threadIdx.x, bid = blockIdx.x;
    for (int b = t; b < NBIN; b += 256) hist[b] = 0;
    __syncthreads();
    int e0 = bid * (N_EDGES / BCNT_BLK);
    int e1 = e0 + (N_EDGES / BCNT_BLK);
    for (int e = e0 + t; e < e1; e += 256) atomicAdd(&hist[dst[e] >> 8], 1);
    __syncthreads();
    for (int b = t; b < NBIN; b += 256) bh[b * BCNT_BLK + bid] = hist[b];
}

__global__ void __launch_bounds__(512) k_binscan(const int* __restrict__ bh,
                                                 int* __restrict__ binoff,
                                                 int* __restrict__ bincur) {
    __shared__ int sc[512];
    int t = threadIdx.x;
    int s = 0;
    if (t < NBIN) {
        const int* row = bh + t * BCNT_BLK;
        for (int k = 0; k < BCNT_BLK; k++) s += row[k];
    }
    sc[t] = s;
    __syncthreads();
    for (int off = 1; off < 512; off <<= 1) {
        int v = (t >= off) ? sc[t - off] : 0;
        __syncthreads();
        sc[t] += v;
        __syncthreads();
    }
    int excl = sc[t] - s;
    if (t <= NBIN) binoff[t] = excl;
    if (t < NBIN) bincur[t] = excl;
}

// pass 1: single coalesced read -> LDS-staged records -> LDS rank -> coalesced write.
__global__ void __launch_bounds__(256) k_part1(const int* __restrict__ src,
                                               const int* __restrict__ dst,
                                               const float* __restrict__ w,
                                               int* __restrict__ bincur,
                                               int2* __restrict__ tmp_sw) {
    __shared__ int2 srec[P1_CHUNK];
    __shared__ unsigned short sbin[P1_CHUNK];
    __shared__ unsigned short sperm[P1_CHUNK];
    __shared__ int hist[NBIN];
    __shared__ int off[NBIN];
    __shared__ int cur[NBIN];
    __shared__ int base[NBIN];
    __shared__ int sc[512];
    int t = threadIdx.x;
    int g0 = blockIdx.x * P1_CHUNK;
    int cn = N_EDGES - g0; if (cn > P1_CHUNK) cn = P1_CHUNK;
    for (int b = t; b < NBIN; b += 256) hist[b] = 0;
    __syncthreads();
    for (int j = t; j < cn; j += 256) {
        int d = dst[g0 + j];
        int b = d >> 8;
        sbin[j] = (unsigned short)b;
        srec[j] = make_int2(src[g0 + j] | ((d & 255) << 20), __float_as_int(w[g0 + j]));
        atomicAdd(&hist[b], 1);
    }
    __syncthreads();
    sc[t] = (t < NBIN) ? hist[t] : 0;
    sc[256 + t] = (256 + t < NBIN) ? hist[256 + t] : 0;
    __syncthreads();
    for (int o = 1; o <= 256; o <<= 1) {
        int v0 = (t >= o) ? sc[t - o] : 0;
        int v1 = sc[256 + t - o];
        __syncthreads();
        sc[t] += v0;
        sc[256 + t] += v1;
        __syncthreads();
    }
    for (int b = t; b < NBIN; b += 256) {
        int e = sc[b] - hist[b];
        off[b] = e;
        cur[b] = e;
        int c = hist[b];
        base[b] = c ? atomicAdd(&bincur[b], c) : 0;
    }
    __syncthreads();
    for (int j = t; j < cn; j += 256) {
        int p = atomicAdd(&cur[sbin[j]], 1);
        sperm[p] = (unsigned short)j;
    }
    __syncthreads();
    for (int p = t; p < cn; p += 256) {
        int j = sperm[p];
        int b = sbin[j];
        tmp_sw[base[b] + (p - off[b])] = srec[j];
    }
}

// pass 2: per-bin fine sort (LDS permute) + ptr; decode dl from record.x
__global__ void __launch_bounds__(256) k_part2(const int2* __restrict__ tmp_sw,
                                               const int* __restrict__ binoff,
                                               int2* __restrict__ er,
                                               int* __restrict__ ptr) {
    __shared__ unsigned char sdl[MAXBIN];
    __shared__ unsigned short perm[MAXBIN];
    __shared__ int hist[256];
    __shared__ int cur[256];
    __shared__ int sc[256];
    int t = threadIdx.x, b = blockIdx.x;
    int nlo = b << 8;
    int e0 = binoff[b], e1 = binoff[b + 1];
    int cnt = e1 - e0;
    int stage = cnt < MAXBIN ? cnt : MAXBIN;
    hist[t] = 0;
    __syncthreads();
    for (int j = t; j < stage; j += 256) {
        unsigned char dl = (unsigned char)((tmp_sw[e0 + j].x >> 20) & 255);
        sdl[j] = dl;
        atomicAdd(&hist[dl], 1);
    }
    for (int j = stage + t; j < cnt; j += 256)
        atomicAdd(&hist[(tmp_sw[e0 + j].x >> 20) & 255], 1);
    __syncthreads();
    int v = hist[t];
    sc[t] = v;
    __syncthreads();
    for (int off = 1; off < 256; off <<= 1) {
        int u = (t >= off) ? sc[t - off] : 0;
        __syncthreads();
        sc[t] += u;
        __syncthreads();
    }
    int excl = sc[t] - v;
    cur[t] = excl;
    if (nlo + t < N_NODES) ptr[nlo + t] = e0 + excl;
    if (b == NBIN - 1 && t == 0) ptr[N_NODES] = N_EDGES;
    __syncthreads();
    for (int j = t; j < stage; j += 256) {
        int p = atomicAdd(&cur[sdl[j]], 1);
        perm[p] = (unsigned short)j;
    }
    __syncthreads();
    for (int j = stage + t; j < cnt; j += 256) {
        int2 sw = tmp_sw[e0 + j];
        int p = atomicAdd(&cur[(sw.x >> 20) & 255], 1);
        er[e0 + p] = make_int2(sw.x & 0xFFFFF, sw.y);
    }
    for (int p = t; p < stage; p += 256) {
        int2 sw = tmp_sw[e0 + perm[p]];
        er[e0 + p] = make_int2(sw.x & 0xFFFFF, sw.y);
    }
}

// ---------------- fp16 conversion of pro_x ----------------
__global__ void k_half1(const float* __restrict__ x, __half* __restrict__ xh,
                        __half* __restrict__ xh32) {
    int i = blockIdx.x * blockDim.x + threadIdx.x;
    if (i < N_NODES * NFP) {
        int n = i / NFP, f = i - n * NFP;
        __half v = __float2half(x[i]);
        if (f < 32) xh[n * ROW1 + f] = v;
        else xh32[n] = v;
    }
}

// ---------------- layer-1 aggregate (33 feats), dual-node in flight ----------------
__global__ void __launch_bounds__(256) k_agg1(
    const __half* __restrict__ xh, const __half* __restrict__ xh32,
    const int* __restrict__ ptr, const int2* __restrict__ er,
    const float* __restrict__ ew, const float* __restrict__ ebv,
    const float* __restrict__ epsp, float* __restrict__ h) {
    int t = threadIdx.x;
    int wave = t >> 6, lane = t & 63;
    int slot = lane >> 2, q = lane & 3;
    float4 ewa = ((const float4*)ew)[q * 2];
    float4 ewb = ((const float4*)ew)[q * 2 + 1];
    float4 eba = ((const float4*)ebv)[q * 2];
    float4 ebb = ((const float4*)ebv)[q * 2 + 1];
    float ew32 = ew[32], eb32 = ebv[32];
    float ep = 1.f + epsp[0];
    for (int quad = blockIdx.x; quad < NQUAD; quad += 2 * AGBLK) {
        int quadB = quad + AGBLK;
        bool hasB = quadB < NQUAD;
        int nodeA = quad * 4 + wave;
        int nodeB = hasB ? quadB * 4 + wave : nodeA;
        float a[8] = {0, 0, 0, 0, 0, 0, 0, 0}, a32 = 0.f;
        float b[8] = {0, 0, 0, 0, 0, 0, 0, 0}, b32 = 0.f;
        int e0a = ptr[nodeA], e1a = ptr[nodeA + 1];
        int e0b = ptr[nodeB], e1b = ptr[nodeB + 1];
        if (!hasB) e1b = e0b;
        int ia = e0a + slot, ib = e0b + slot;
        while (ia < e1a || ib < e1b) {
            bool da = ia < e1a, db = ib < e1b;
            int2 edA, edB;
            if (da) edA = er[ia];
            if (db) edB = er[ib];
            uint4 rA, rB;
            float wvA = 0.f, wvB = 0.f;
            float x32A = 0.f, x32B = 0.f;
            if (da) {
                rA = *(const uint4*)(xh + edA.x * ROW1 + q * 8);
                wvA = __int_as_float(edA.y);
                if (q == 0) x32A = __half2float(xh32[edA.x]);
            }
            if (db) {
                rB = *(const uint4*)(xh + edB.x * ROW1 + q * 8);
                wvB = __int_as_float(edB.y);
                if (q == 0) x32B = __half2float(xh32[edB.x]);
            }
            if (da) {
                float2 f01 = __half22float2(*(__half2*)&rA.x);
                float2 f23 = __half22float2(*(__half2*)&rA.y);
                float2 f45 = __half22float2(*(__half2*)&rA.z);
                float2 f67 = __half22float2(*(__half2*)&rA.w);
                a[0] += fmaxf(f01.x + wvA * ewa.x + eba.x, 0.f);
                a[1] += fmaxf(f01.y + wvA * ewa.y + eba.y, 0.f);
                a[2] += fmaxf(f23.x + wvA * ewa.z + eba.z, 0.f);
                a[3] += fmaxf(f23.y + wvA * ewa.w + eba.w, 0.f);
                a[4] += fmaxf(f45.x + wvA * ewb.x + ebb.x, 0.f);
                a[5] += fmaxf(f45.y + wvA * ewb.y + ebb.y, 0.f);
                a[6] += fmaxf(f67.x + wvA * ewb.z + ebb.z, 0.f);
                a[7] += fmaxf(f67.y + wvA * ewb.w + ebb.w, 0.f);
                if (q == 0) a32 += fmaxf(x32A + wvA * ew32 + eb32, 0.f);
            }
            if (db) {
                float2 f01 = __half22float2(*(__half2*)&rB.x);
                float2 f23 = __half22float2(*(__half2*)&rB.y);
                float2 f45 = __half22float2(*(__half2*)&rB.z);
                float2 f67 = __half22float2(*(__half2*)&rB.w);
                b[0] += fmaxf(f01.x + wvB * ewa.x + eba.x, 0.f);
                b[1] += fmaxf(f01.y + wvB * ewa.y + eba.y, 0.f);
                b[2] += fmaxf(f23.x + wvB * ewa.z + eba.z, 0.f);
                b[3] += fmaxf(f23.y + wvB * ewa.w + eba.w, 0.f);
                b[4] += fmaxf(f45.x + wvB * ewb.x + ebb.x, 0.f);
                b[5] += fmaxf(f45.y + wvB * ewb.y + ebb.y, 0.f);
                b[6] += fmaxf(f67.x + wvB * ewb.z + ebb.z, 0.f);
                b[7] += fmaxf(f67.y + wvB * ewb.w + ebb.w, 0.f);
                if (q == 0) b32 += fmaxf(x32B + wvB * ew32 + eb32, 0.f);
            }
            ia += 16; ib += 16;
        }
        #pragma unroll
        for (int m = 4; m <= 32; m <<= 1) {
            #pragma unroll
            for (int j = 0; j < 8; j++) {
                a[j] += __shfl_xor(a[j], m);
                b[j] += __shfl_xor(b[j], m);
            }
            a32 += __shfl_xor(a32, m);
            b32 += __shfl_xor(b32, m);
        }
        if (slot == 0) {
            {
                uint4 sraw = *(const uint4*)(xh + nodeA * ROW1 + q * 8);
                float2 s01 = __half22float2(*(__half2*)&sraw.x);
                float2 s23 = __half22float2(*(__half2*)&sraw.y);
                float2 s45 = __half22float2(*(__half2*)&sraw.z);
                float2 s67 = __half22float2(*(__half2*)&sraw.w);
                float* hp = h + nodeA * H1STR + q * 8;
                *(float4*)hp = make_float4(ep * s01.x + a[0], ep * s01.y + a[1],
                                           ep * s23.x + a[2], ep * s23.y + a[3]);
                *(float4*)(hp + 4) = make_float4(ep * s45.x + a[4], ep * s45.y + a[5],
                                                 ep * s67.x + a[6], ep * s67.y + a[7]);
                if (q == 0)
                    h[nodeA * H1STR + 32] = ep * __half2float(xh32[nodeA]) + a32;
            }
            if (hasB) {
                uint4 sraw = *(const uint4*)(xh + nodeB * ROW1 + q * 8);
                float2 s01 = __half22float2(*(__half2*)&sraw.x);
                float2 s23 = __half22float2(*(__half2*)&sraw.y);
                float2 s45 = __half22float2(*(__half2*)&sraw.z);
                float2 s67 = __half22float2(*(__half2*)&sraw.w);
                float* hp = h + nodeB * H1STR + q * 8;
                *(float4*)hp = make_float4(ep * s01.x + b[0], ep * s01.y + b[1],
                                           ep * s23.x + b[2], ep * s23.y + b[3]);
                *(float4*)(hp + 4) = make_float4(ep * s45.x + b[4], ep * s45.y + b[5],
                                                 ep * s67.x + b[6], ep * s67.y + b[7]);
                if (q == 0)
                    h[nodeB * H1STR + 32] = ep * __half2float(xh32[nodeB]) + b32;
            }
        }
    }
}

// ---------------- layer 2-5 aggregate (16 feats), BN folded, dual-node ----------------
__global__ void __launch_bounds__(256) k_agg16(
    const __half* __restrict__ zh, const int* __restrict__ ptr,
    const int2* __restrict__ er,
    const float* __restrict__ ew, const float* __restrict__ ebv,
    const float* __restrict__ epsp,
    const float* __restrict__ bnstat, const float* __restrict__ gamma,
    const float* __restrict__ beta, float* __restrict__ h) {
    int t = threadIdx.x;
    int wave = t >> 6, lane = t & 63;
    int slot = lane >> 1, hh = lane & 1;
    float ep = 1.f + epsp[0];
    const float invn = 1.f / (float)N_NODES;
    float scf[8], shf[8], cbf[8], ewf[8];
    #pragma unroll
    for (int j = 0; j < 8; j++) {
        int f = hh * 8 + j;
        float mu = bnstat[f] * invn;
        float var = bnstat[DIM + f] * invn - mu * mu;
        float sc = gamma[f] * rsqrtf(var + BN_EPSV);
        scf[j] = sc;
        shf[j] = beta[f] - mu * sc;
        cbf[j] = shf[j] + ebv[f];
        ewf[j] = ew[f];
    }
    for (int quad = blockIdx.x; quad < NQUAD; quad += 2 * AGBLK) {
        int quadB = quad + AGBLK;
        bool hasB = quadB < NQUAD;
        int nodeA = quad * 4 + wave;
        int nodeB = hasB ? quadB * 4 + wave : nodeA;
        float a[8] = {0, 0, 0, 0, 0, 0, 0, 0};
        float b[8] = {0, 0, 0, 0, 0, 0, 0, 0};
        int e0a = ptr[nodeA], e1a = ptr[nodeA + 1];
        int e0b = ptr[nodeB], e1b = ptr[nodeB + 1];
        if (!hasB) e1b = e0b;
        int ia = e0a + slot, ib = e0b + slot;
        while (ia < e1a || ib < e1b) {
            bool da = ia < e1a, db = ib < e1b;
            int2 edA, edB;
            if (da) edA = er[ia];
            if (db) edB = er[ib];
            uint4 rA, rB;
            float wvA = 0.f, wvB = 0.f;
            if (da) { rA = *(const uint4*)(zh + edA.x * DIM + hh * 8); wvA = __int_as_float(edA.y); }
            if (db) { rB = *(const uint4*)(zh + edB.x * DIM + hh * 8); wvB = __int_as_float(edB.y); }
            if (da) {
                float2 f01 = __half22float2(*(__half2*)&rA.x);
                float2 f23 = __half22float2(*(__half2*)&rA.y);
                float2 f45 = __half22float2(*(__half2*)&rA.z);
                float2 f67 = __half22float2(*(__half2*)&rA.w);
                float x[8] = {f01.x, f01.y, f23.x, f23.y, f45.x, f45.y, f67.x, f67.y};
                #pragma unroll
                for (int j = 0; j < 8; j++) {
                    float tb = fmaf(wvA, ewf[j], cbf[j]);
                    a[j] += fmaxf(fmaf(x[j], scf[j], tb), 0.f);
                }
            }
            if (db) {
                float2 f01 = __half22float2(*(__half2*)&rB.x);
                float2 f23 = __half22float2(*(__half2*)&rB.y);
                float2 f45 = __half22float2(*(__half2*)&rB.z);
                float2 f67 = __half22float2(*(__half2*)&rB.w);
                float x[8] = {f01.x, f01.y, f23.x, f23.y, f45.x, f45.y, f67.x, f67.y};
                #pragma unroll
                for (int j = 0; j < 8; j++) {
                    float tb = fmaf(wvB, ewf[j], cbf[j]);
                    b[j] += fmaxf(fmaf(x[j], scf[j], tb), 0.f);
                }
            }
            ia += 32; ib += 32;
        }
        #pragma unroll
        for (int m = 2; m <= 32; m <<= 1) {
            #pragma unroll
            for (int j = 0; j < 8; j++) {
                a[j] += __shfl_xor(a[j], m);
                b[j] += __shfl_xor(b[j], m);
            }
        }
        if (lane < 2) {
            {
                uint4 sraw = *(const uint4*)(zh + nodeA * DIM + lane * 8);
                float2 s01 = __half22float2(*(__half2*)&sraw.x);
                float2 s23 = __half22float2(*(__half2*)&sraw.y);
                float2 s45 = __half22float2(*(__half2*)&sraw.z);
                float2 s67 = __half22float2(*(__half2*)&sraw.w);
                float xs[8] = {s01.x, s01.y, s23.x, s23.y, s45.x, s45.y, s67.x, s67.y};
                float o8[8];
                #pragma unroll
                for (int j = 0; j < 8; j++)
                    o8[j] = ep * fmaf(xs[j], scf[j], shf[j]) + a[j];
                float* hp = h + nodeA * DIM + lane * 8;
                *(float4*)hp = make_float4(o8[0], o8[1], o8[2], o8[3]);
                *(float4*)(hp + 4) = make_float4(o8[4], o8[5], o8[6], o8[7]);
            }
            if (hasB) {
                uint4 sraw = *(const uint4*)(zh + nodeB * DIM + lane * 8);
                float2 s01 = __half22float2(*(__half2*)&sraw.x);
                float2 s23 = __half22float2(*(__half2*)&sraw.y);
                float2 s45 = __half22float2(*(__half2*)&sraw.z);
                float2 s67 = __half22float2(*(__half2*)&sraw.w);
                float xs[8] = {s01.x, s01.y, s23.x, s23.y, s45.x, s45.y, s67.x, s67.y};
                float o8[8];
                #pragma unroll
                for (int j = 0; j < 8; j++)
                    o8[j] = ep * fmaf(xs[j], scf[j], shf[j]) + b[j];
                float* hp = h + nodeB * DIM + lane * 8;
                *(float4*)hp = make_float4(o8[0], o8[1], o8[2], o8[3]);
                *(float4*)(hp + 4) = make_float4(o8[4], o8[5], o8[6], o8[7]);
            }
        }
    }
}

// ---------------- fused per-thread MLP + shfl-reduced BN partials, fp16 z out ----------------
__device__ __forceinline__ void mlp_bn_tail(float zv[16], bool active, int t,
                                            float* __restrict__ part) {
    __shared__ float red[4][32];
    float zs[16], zq[16];
    #pragma unroll
    for (int o = 0; o < 16; o++) {
        zs[o] = active ? zv[o] : 0.f;
        zq[o] = active ? zv[o] * zv[o] : 0.f;
    }
    #pragma unroll
    for (int m = 1; m <= 32; m <<= 1) {
        #pragma unroll
        for (int o = 0; o < 16; o++) {
            zs[o] += __shfl_xor(zs[o], m);
            zq[o] += __shfl_xor(zq[o], m);
        }
    }
    int wave = t >> 6, lane = t & 63;
    if (lane == 0) {
        #pragma unroll
        for (int o = 0; o < 16; o++) {
            red[wave][o] = zs[o];
            red[wave][16 + o] = zq[o];
        }
    }
    __syncthreads();
    if (t < 32)
        part[blockIdx.x * 32 + t] = red[0][t] + red[1][t] + red[2][t] + red[3][t];
}

__device__ __forceinline__ void store_zh(__half* __restrict__ zh, int n, float zv[16]) {
    __half2 p[8];
    #pragma unroll
    for (int j = 0; j < 8; j++) p[j] = __floats2half2_rn(zv[2 * j], zv[2 * j + 1]);
    *(uint4*)(zh + n * DIM) = *(uint4*)&p[0];
    *(uint4*)(zh + n * DIM + 8) = *(uint4*)&p[4];
}

__global__ void __launch_bounds__(256) k_mlp16(
    const float* __restrict__ h,
    const float* __restrict__ W1, const float* __restrict__ b1,
    const float* __restrict__ W2, const float* __restrict__ b2,
    __half* __restrict__ zh, float* __restrict__ part) {
    __shared__ float W1s[256], W2s[256], b1s[16], b2s[16];
    int t = threadIdx.x;
    W1s[t] = W1[t];
    W2s[t] = W2[t];
    if (t < 16) { b1s[t] = b1[t]; b2s[t] = b2[t]; }
    __syncthreads();
    int n = blockIdx.x * 256 + t;
    bool active = n < N_NODES;
    float zv[16];
    if (active) {
        float hv[16];
        #pragma unroll
        for (int j = 0; j < 4; j++) {
            float4 v = *(const float4*)(h + n * DIM + j * 4);
            hv[j * 4] = v.x; hv[j * 4 + 1] = v.y; hv[j * 4 + 2] = v.z; hv[j * 4 + 3] = v.w;
        }
        float tv[16];
        #pragma unroll
        for (int o = 0; o < 16; o++) {
            float s = b1s[o];
            #pragma unroll
            for (int f = 0; f < 16; f++) s += hv[f] * W1s[f * 16 + o];
            tv[o] = fmaxf(s, 0.f);
        }
        #pragma unroll
        for (int o = 0; o < 16; o++) {
            float s = b2s[o];
            #pragma unroll
            for (int f = 0; f < 16; f++) s += tv[f] * W2s[f * 16 + o];
            zv[o] = fmaxf(s, 0.f);
        }
        store_zh(zh, n, zv);
    }
    mlp_bn_tail(zv, active, t, part);
}

__global__ void __launch_bounds__(256) k_mlp1(
    const float* __restrict__ h,
    const float* __restrict__ W1, const float* __restrict__ b1,
    const float* __restrict__ W2, const float* __restrict__ b2,
    __half* __restrict__ zh, float* __restrict__ part) {
    __shared__ float W1s[NFP * 16], W2s[256], b1s[16], b2s[16];
    int t = threadIdx.x;
    for (int j = t; j < NFP * 16; j += 256) W1s[j] = W1[j];
    W2s[t] = W2[t];
    if (t < 16) { b1s[t] = b1[t]; b2s[t] = b2[t]; }
    __syncthreads();
    int n = blockIdx.x * 256 + t;
    bool active = n < N_NODES;
    float zv[16];
    if (active) {
        float hv[NFP];
        #pragma unroll
        for (int j = 0; j < 8; j++) {
            float4 v = *(const float4*)(h + n * H1STR + j * 4);
            hv[j * 4] = v.x; hv[j * 4 + 1] = v.y; hv[j * 4 + 2] = v.z; hv[j * 4 + 3] = v.w;
        }
        hv[32] = h[n * H1STR + 32];
        float tv[16];
        #pragma unroll
        for (int o = 0; o < 16; o++) {
            float s = b1s[o];
            #pragma unroll
            for (int f = 0; f < NFP; f++) s += hv[f] * W1s[f * 16 + o];
            tv[o] = fmaxf(s, 0.f);
        }
        #pragma unroll
        for (int o = 0; o < 16; o++) {
            float s = b2s[o];
            #pragma unroll
            for (int f = 0; f < 16; f++) s += tv[f] * W2s[f * 16 + o];
            zv[o] = fmaxf(s, 0.f);
        }
        store_zh(zh, n, zv);
    }
    mlp_bn_tail(zv, active, t, part);
}

// ---------------- reduce block partials -> bnstat[32] ----------------
__global__ void __launch_bounds__(1024) k_bnred(const float* __restrict__ part,
                                                float* __restrict__ bnstat) {
    __shared__ float red[1024];
    int t = threadIdx.x;
    int f = t & 31, g = t >> 5;
    float s = 0.f;
    for (int i = g; i < MLPB; i += 32) s += part[i * 32 + f];
    red[t] = s;
    __syncthreads();
    for (int off = 512; off >= 32; off >>= 1) {
        if (t < off) red[t] += red[t + off];
        __syncthreads();
    }
    if (t < 32) bnstat[t] = red[t];
}

// ---------------- pooling with BN folded in ----------------
__global__ void __launch_bounds__(256) k_pool(const __half* __restrict__ zh,
                                              const int* __restrict__ batch,
                                              const float* __restrict__ bnstat,
                                              const float* __restrict__ gamma,
                                              const float* __restrict__ beta,
                                              float* __restrict__ gsum,
                                              float* __restrict__ gcnt) {
    __shared__ float lsum[BGR * DIM];
    __shared__ float lcnt[BGR];
    int t = threadIdx.x;
    for (int j = t; j < BGR * DIM; j += 256) lsum[j] = 0.f;
    if (t < BGR) lcnt[t] = 0.f;
    __syncthreads();
    int f = t & 15, r = t >> 4;
    const float invn = 1.f / (float)N_NODES;
    float mu = bnstat[f] * invn;
    float var = bnstat[DIM + f] * invn - mu * mu;
    float sc = gamma[f] * rsqrtf(var + BN_EPSV);
    float sh = beta[f] - mu * sc;
    int start = blockIdx.x * POOL_CHUNK;
    float acc = 0.f, cacc = 0.f;
    int cur = -1;
    for (int i = 0; i < POOL_CHUNK / 16; i++) {
        int n = start + r + i * 16;
        if (n >= N_NODES) break;
        int b = batch[n];
        if (b != cur) {
            if (cur >= 0) {
                atomicAdd(&lsum[cur * DIM + f], acc);
                if (f == 0) atomicAdd(&lcnt[cur], cacc);
            }
            cur = b; acc = 0.f; cacc = 0.f;
        }
        acc += fmaf(__half2float(zh[n * DIM + f]), sc, sh);
        cacc += 1.f;
    }
    if (cur >= 0) {
        atomicAdd(&lsum[cur * DIM + f], acc);
        if (f == 0) atomicAdd(&lcnt[cur], cacc);
    }
    __syncthreads();
    for (int j = t; j < BGR * DIM; j += 256) {
        float v = lsum[j];
        if (v != 0.f) atomicAdd(&gsum[j], v);
    }
    if (t < BGR) {
        float v = lcnt[t];
        if (v != 0.f) atomicAdd(&gcnt[t], v);
    }
}

__global__ void k_xp(const float* __restrict__ gsum, const float* __restrict__ gcnt,
                     const float* __restrict__ w, const float* __restrict__ bias,
                     float* __restrict__ out) {
    int b = blockIdx.x;
    int e = threadIdx.x;
    float inv = 1.f / fmaxf(gcnt[b], 1.f);
    float acc = bias[e];
    #pragma unroll
    for (int f = 0; f < DIM; f++) acc += gsum[b * DIM + f] * inv * w[f * EMB + e];
    out[b * EMB + e] = fmaxf(acc, 0.f);
}

// ---------------- RNA ----------------
__global__ void __launch_bounds__(256) k_bucket(const int* __restrict__ tok, int L, int V,
                                                int* __restrict__ blist,
                                                int* __restrict__ bptr) {
    __shared__ int hist[65];
    __shared__ int cursor[65];
    int b = blockIdx.x, t = threadIdx.x;
    if (t < V) hist[t] = 0;
    __syncthreads();
    for (int l = t; l < L; l += 256) atomicAdd(&hist[tok[b * L + l]], 1);
    __syncthreads();
    if (t == 0) {
        int run = 0;
        for (int v = 0; v < V; v++) {
            cursor[v] = run;
            bptr[b * (V + 1) + v] = run;
            run += hist[v];
        }
        bptr[b * (V + 1) + V] = run;
    }
    __syncthreads();
    for (int l = t; l < L; l += 256) {
        int v = tok[b * L + l];
        int p = atomicAdd(&cursor[v], 1);
        blist[b * L + p] = l;
    }
}

__global__ void __launch_bounds__(256) k_wsum(const int* __restrict__ blist,
                                              const int* __restrict__ bptr,
                                              const float* __restrict__ cw,
                                              float* __restrict__ W, int L, int V) {
    int b = blockIdx.x, v = blockIdx.y;
    int t = threadIdx.x, o = t >> 3, k = t & 7;
    int s = bptr[b * (V + 1) + v], e = bptr[b * (V + 1) + v + 1];
    __shared__ int tk[256];
    const float* cwp = cw + o * (L * KS) + k;
    float acc = 0.f;
    for (int j0 = s; j0 < e; j0 += 256) {
        int lim = e - j0; if (lim > 256) lim = 256;
        __syncthreads();
        if (t < lim) tk[t] = blist[b * L + j0 + t];
        __syncthreads();
        for (int j = 0; j < lim; j++) acc += cwp[tk[j] * KS];
    }
    W[((b * NF + o) * V + v) * KS + k] = acc;
}

__global__ void k_y(const float* __restrict__ Wg, const float* __restrict__ Wl,
                    const float* __restrict__ emb1, const float* __restrict__ emb2,
                    const float* __restrict__ cb1, const float* __restrict__ cb2,
                    float* __restrict__ yg, float* __restrict__ yl) {
    int which = blockIdx.y;
    int bo = blockIdx.x;
    int b = bo >> 5, o = bo & 31;
    int t = threadIdx.x;  // 128
    const float* W = which ? Wl : Wg;
    const float* emb = which ? emb2 : emb1;
    const float* cb = which ? cb2 : cb1;
    float* y = which ? yl : yg;
    int V = which ? 65 : 5;
    __shared__ float Wsh[65 * KS];
    const float* Wrow = W + (b * NF + o) * V * KS;
    for (int j = t; j < V * KS; j += 128) Wsh[j] = Wrow[j];
    __syncthreads();
    if (t < OUTT) {
        float acc = cb[o];
        for (int v = 0; v < V; v++) {
            const float* ep = emb + v * EMB + t;
            #pragma unroll
            for (int k = 0; k < KS; k++) acc += Wsh[v * KS + k] * ep[k];
        }
        y[(b * NF + o) * OUTT + t] = acc;
    }
}

__global__ void __launch_bounds__(128) k_fcpart(const float* __restrict__ yg,
                                                const float* __restrict__ yl,
                                                const float* __restrict__ w,
                                                float* __restrict__ partial) {
    int b = blockIdx.x, which = blockIdx.y, kc = blockIdx.z;
    const float* y = which ? yl : yg;
    int e = threadIdx.x;
    __shared__ float ych[KCH];
    int j0 = kc * KCH;
    if (e < KCH) ych[e] = y[b * FC_IN + j0 + e];
    __syncthreads();
    float acc = 0.f;
    #pragma unroll 4
    for (int jj = 0; jj < KCH; jj++) acc += ych[jj] * w[(j0 + jj) * EMB + e];
    partial[((which * BGR + b) * NKC + kc) * EMB + e] = acc;
}

__global__ void k_fcred(const float* __restrict__ partial, const float* __restrict__ bias,
                        float* __restrict__ out) {
    int b = blockIdx.x;
    int e = threadIdx.x;
    const float* pg = partial + b * NKC * EMB + e;
    const float* pl = partial + (BGR + b) * NKC * EMB + e;
    float ag = bias[e], al = bias[e];
    #pragma unroll
    for (int k = 0; k < NKC; k++) { ag += pg[k * EMB]; al += pl[k * EMB]; }
    out[b * EMB + e] = 0.5f * (ag + al);
}

extern "C" void kernel_launch(void* const* d_in, const int* in_sizes, int n_in,
                              void* d_out, int out_size, void* d_ws, size_t ws_size,
                              hipStream_t stream) {
    const float* pro_x = (const float*)d_in[0];
    const int* eidx = (const int*)d_in[1];
    const int* esrc = eidx;
    const int* edst = eidx + N_EDGES;
    const float* pw = (const float*)d_in[2];
    const int* batch = (const int*)d_in[3];
    const int* rg = (const int*)d_in[4];
    const int* rl = (const int*)d_in[5];
    const float* g1_w1 = (const float*)d_in[6];
    const float* g1_b1 = (const float*)d_in[7];
    const float* g1_w2 = (const float*)d_in[8];
    const float* g1_b2 = (const float*)d_in[9];
    const float* g1_ew = (const float*)d_in[10];
    const float* g1_eb = (const float*)d_in[11];
    const float* g1_eps = (const float*)d_in[12];
    const float* g_w1 = (const float*)d_in[13];
    const float* g_b1 = (const float*)d_in[14];
    const float* g_w2 = (const float*)d_in[15];
    const float* g_b2 = (const float*)d_in[16];
    const float* g_ew = (const float*)d_in[17];
    const float* g_eb = (const float*)d_in[18];
    const float* g_eps = (const float*)d_in[19];
    const float* bn_gamma = (const float*)d_in[20];
    const float* bn_beta = (const float*)d_in[21];
    const float* fc1_xp_w = (const float*)d_in[22];
    const float* fc1_xp_b = (const float*)d_in[23];
    const float* emb1 = (const float*)d_in[24];
    const float* emb2 = (const float*)d_in[25];
    const float* convr1_w = (const float*)d_in[26];
    const float* convr1_b = (const float*)d_in[27];
    const float* convr2_w = (const float*)d_in[28];
    const float* convr2_b = (const float*)d_in[29];
    const float* fcxr_w = (const float*)d_in[30];
    const float* fcxr_b = (const float*)d_in[31];
    float* out = (float*)d_out;

    // persistent buffers
    float* wsf = (float*)d_ws;
    int* ptr       = (int*)wsf;        wsf += 100128;
    int* binoff    = (int*)wsf;        wsf += 512;
    int* bincur    = (int*)wsf;        wsf += 512;
    int2* er       = (int2*)wsf;       wsf += 2 * N_EDGES;
    float* stats   = wsf;              wsf += 1280;
    // union region
    float* un = wsf;
    int2* tmp_sw          = (int2*)un;
    int* bh               = (int*)(un + 7200000);
    __half* zh   = (__half*)(un + 1600000);
    __half* xh1  = (__half*)(un + 2400000);
    __half* xh32 = (__half*)(un + 4000000);
    float* bpart = un + 4100000;
    float* Wg    = un + 4300000;
    float* Wl    = un + 4382000;
    float* yg    = un + 5447000;
    float* yl    = un + 5695000;
    int* blg     = (int*)(un + 5961000);
    int* bll     = (int*)(un + 6153000);
    int* bpg     = (int*)(un + 6345000);
    int* bpl     = (int*)(un + 6346000);
    float* fcpart = un + 6360000;
    float* h      = un + 7400000;
    float* gsum   = stats;
    float* gcnt   = stats + 1024;
    float* bnstat = stats + 1088;

    hipMemsetAsync(stats, 0, 1280 * sizeof(float), stream);

    // CSR build
    k_bincnt<<<BCNT_BLK, 256, 0, stream>>>(edst, bh);
    k_binscan<<<1, 512, 0, stream>>>(bh, binoff, bincur);
    k_part1<<<P1_BLOCKS, 256, 0, stream>>>(esrc, edst, pw, bincur, tmp_sw);
    k_part2<<<NBIN, 256, 0, stream>>>(tmp_sw, binoff, er, ptr);

    // pro_x -> fp16 rows
    k_half1<<<(N_NODES * NFP + 255) / 256, 256, 0, stream>>>(pro_x, xh1, xh32);

    // RNA branch
    k_bucket<<<BGR, 256, 0, stream>>>(rg, MAXLEN, 5, blg, bpg);
    k_bucket<<<BGR, 256, 0, stream>>>(rl, LOCLEN, 65, bll, bpl);
    k_wsum<<<dim3(BGR, 5), 256, 0, stream>>>(blg, bpg, convr1_w, Wg, MAXLEN, 5);
    k_wsum<<<dim3(BGR, 65), 256, 0, stream>>>(bll, bpl, convr2_w, Wl, LOCLEN, 65);
    k_y<<<dim3(BGR * NF, 2), 128, 0, stream>>>(Wg, Wl, emb1, emb2, convr1_b, convr2_b, yg, yl);
    k_fcpart<<<dim3(BGR, 2, NKC), 128, 0, stream>>>(yg, yl, fcxr_w, fcpart);
    k_fcred<<<BGR, 128, 0, stream>>>(fcpart, fcxr_b, out);

    // GNN stack
    k_agg1<<<AGBLK, 256, 0, stream>>>(xh1, xh32, ptr, er, g1_ew, g1_eb, g1_eps, h);
    k_mlp1<<<MLPB, 256, 0, stream>>>(h, g1_w1, g1_b1, g1_w2, g1_b2, zh, bpart);
    k_bnred<<<1, 1024, 0, stream>>>(bpart, bnstat);
    for (int i = 0; i < 4; i++) {
        k_agg16<<<AGBLK, 256, 0, stream>>>(zh, ptr, er,
                                           g_ew + i * DIM, g_eb + i * DIM, g_eps + i,
                                           bnstat + i * 32, bn_gamma + i * DIM,
                                           bn_beta + i * DIM, h);
        k_mlp16<<<MLPB, 256, 0, stream>>>(h, g_w1 + i * DIM * DIM, g_b1 + i * DIM,
                                          g_w2 + i * DIM * DIM, g_b2 + i * DIM, zh, bpart);
        k_bnred<<<1, 1024, 0, stream>>>(bpart, bnstat + (i + 1) * 32);
    }
    k_pool<<<POOL_BLKS, 256, 0, stream>>>(zh, batch, bnstat + 4 * 32,
                                          bn_gamma + 4 * DIM, bn_beta + 4 * DIM, gsum, gcnt);
    k_xp<<<BGR, EMB, 0, stream>>>(gsum, gcnt, fc1_xp_w, fc1_xp_b, out + BGR * EMB);
}

// Round 15
// 782.245 us; speedup vs baseline: 1.0319x; 1.0319x over previous
//
#include <hip/hip_runtime.h>
#include <hip/hip_fp16.h>

#define N_NODES 100000
#define N_EDGES 3200000
#define BGR 64
#define DIM 16
#define NFP 33
#define ROW1 32
#define H1STR 36
#define EMB 128
#define MAXLEN 3000
#define LOCLEN 2998
#define NF 32
#define KS 8
#define OUTT 121
#define FC_IN 3872
#define BN_EPSV 1e-5f
#define POOL_CHUNK 256
#define POOL_BLKS 391
#define NQUAD 25000
#define AGBLK 2048
#define MLPB 391
// binned CSR build
#define NBIN 391
#define BCNT_BLK 512
#define P1_CHUNK 4096
#define P1_BLOCKS 782
#define MAXBIN 9088
// fc K-split
#define NKC 32
#define KCH 121
#define WDEC (1.f / 32767.f)

// ---------------- CSR build ----------------
__global__ void __launch_bounds__(256) k_bincnt(const int* __restrict__ dst,
                                                int* __restrict__ bh) {
    __shared__ int hist[NBIN];
    int t = threadIdx.x, bid = blockIdx.x;
    for (int b = t; b < NBIN; b += 256) hist[b] = 0;
    __syncthreads();
    int e0 = bid * (N_EDGES / BCNT_BLK);
    int e1 = e0 + (N_EDGES / BCNT_BLK);
    for (int e = e0 + t; e < e1; e += 256) atomicAdd(&hist[dst[e] >> 8], 1);
    __syncthreads();
    for (int b = t; b < NBIN; b += 256) bh[b * BCNT_BLK + bid] = hist[b];
}

__global__ void __launch_bounds__(512) k_binscan(const int* __restrict__ bh,
                                                 int* __restrict__ binoff,
                                                 int* __restrict__ bincur) {
    __shared__ int sc[512];
    int t = threadIdx.x;
    int s = 0;
    if (t < NBIN) {
        const int* row = bh + t * BCNT_BLK;
        for (int k = 0; k < BCNT_BLK; k++) s += row[k];
    }
    sc[t] = s;
    __syncthreads();
    for (int off = 1; off < 512; off <<= 1) {
        int v = (t >= off) ? sc[t - off] : 0;
        __syncthreads();
        sc[t] += v;
        __syncthreads();
    }
    int excl = sc[t] - s;
    if (t <= NBIN) binoff[t] = excl;
    if (t < NBIN) bincur[t] = excl;
}

// pass 1: single coalesced read -> LDS-staged records -> LDS rank -> coalesced write.
__global__ void __launch_bounds__(256) k_part1(const int* __restrict__ src,
                                               const int* __restrict__ dst,
                                               const float* __restrict__ w,
                                               int* __restrict__ bincur,
                                               int2* __restrict__ tmp_sw) {
    __shared__ int2 srec[P1_CHUNK];
    __shared__ unsigned short sbin[P1_CHUNK];
    __shared__ unsigned short sperm[P1_CHUNK];
    __shared__ int hist[NBIN];
    __shared__ int off[NBIN];
    __shared__ int cur[NBIN];
    __shared__ int base[NBIN];
    __shared__ int sc[512];
    int t = threadIdx.x;
    int g0 = blockIdx.x * P1_CHUNK;
    int cn = N_EDGES - g0; if (cn > P1_CHUNK) cn = P1_CHUNK;
    for (int b = t; b < NBIN; b += 256) hist[b] = 0;
    __syncthreads();
    for (int j = t; j < cn; j += 256) {
        int d = dst[g0 + j];
        int b = d >> 8;
        sbin[j] = (unsigned short)b;
        srec[j] = make_int2(src[g0 + j] | ((d & 255) << 20), __float_as_int(w[g0 + j]));
        atomicAdd(&hist[b], 1);
    }
    __syncthreads();
    sc[t] = (t < NBIN) ? hist[t] : 0;
    sc[256 + t] = (256 + t < NBIN) ? hist[256 + t] : 0;
    __syncthreads();
    for (int o = 1; o <= 256; o <<= 1) {
        int v0 = (t >= o) ? sc[t - o] : 0;
        int v1 = sc[256 + t - o];
        __syncthreads();
        sc[t] += v0;
        sc[256 + t] += v1;
        __syncthreads();
    }
    for (int b = t; b < NBIN; b += 256) {
        int e = sc[b] - hist[b];
        off[b] = e;
        cur[b] = e;
        int c = hist[b];
        base[b] = c ? atomicAdd(&bincur[b], c) : 0;
    }
    __syncthreads();
    for (int j = t; j < cn; j += 256) {
        int p = atomicAdd(&cur[sbin[j]], 1);
        sperm[p] = (unsigned short)j;
    }
    __syncthreads();
    for (int p = t; p < cn; p += 256) {
        int j = sperm[p];
        int b = sbin[j];
        tmp_sw[base[b] + (p - off[b])] = srec[j];
    }
}

// pass 2: per-bin fine sort + ptr; emit compact 4B edge records src(17) | wq(15)
__global__ void __launch_bounds__(256) k_part2(const int2* __restrict__ tmp_sw,
                                               const int* __restrict__ binoff,
                                               unsigned* __restrict__ er,
                                               int* __restrict__ ptr) {
    __shared__ unsigned char sdl[MAXBIN];
    __shared__ unsigned short perm[MAXBIN];
    __shared__ int hist[256];
    __shared__ int cur[256];
    __shared__ int sc[256];
    int t = threadIdx.x, b = blockIdx.x;
    int nlo = b << 8;
    int e0 = binoff[b], e1 = binoff[b + 1];
    int cnt = e1 - e0;
    int stage = cnt < MAXBIN ? cnt : MAXBIN;
    hist[t] = 0;
    __syncthreads();
    for (int j = t; j < stage; j += 256) {
        unsigned char dl = (unsigned char)((tmp_sw[e0 + j].x >> 20) & 255);
        sdl[j] = dl;
        atomicAdd(&hist[dl], 1);
    }
    for (int j = stage + t; j < cnt; j += 256)
        atomicAdd(&hist[(tmp_sw[e0 + j].x >> 20) & 255], 1);
    __syncthreads();
    int v = hist[t];
    sc[t] = v;
    __syncthreads();
    for (int off = 1; off < 256; off <<= 1) {
        int u = (t >= off) ? sc[t - off] : 0;
        __syncthreads();
        sc[t] += u;
        __syncthreads();
    }
    int excl = sc[t] - v;
    cur[t] = excl;
    if (nlo + t < N_NODES) ptr[nlo + t] = e0 + excl;
    if (b == NBIN - 1 && t == 0) ptr[N_NODES] = N_EDGES;
    __syncthreads();
    for (int j = t; j < stage; j += 256) {
        int p = atomicAdd(&cur[sdl[j]], 1);
        perm[p] = (unsigned short)j;
    }
    __syncthreads();
    for (int j = stage + t; j < cnt; j += 256) {
        int2 sw = tmp_sw[e0 + j];
        int p = atomicAdd(&cur[(sw.x >> 20) & 255], 1);
        unsigned wq = (unsigned)(__int_as_float(sw.y) * 32767.f + 0.5f);
        er[e0 + p] = ((unsigned)sw.x & 0x1FFFFu) | (wq << 17);
    }
    for (int p = t; p < stage; p += 256) {
        int2 sw = tmp_sw[e0 + perm[p]];
        unsigned wq = (unsigned)(__int_as_float(sw.y) * 32767.f + 0.5f);
        er[e0 + p] = ((unsigned)sw.x & 0x1FFFFu) | (wq << 17);
    }
}

// ---------------- fp16 conversion of pro_x ----------------
__global__ void k_half1(const float* __restrict__ x, __half* __restrict__ xh,
                        __half* __restrict__ xh32) {
    int i = blockIdx.x * blockDim.x + threadIdx.x;
    if (i < N_NODES * NFP) {
        int n = i / NFP, f = i - n * NFP;
        __half v = __float2half(x[i]);
        if (f < 32) xh[n * ROW1 + f] = v;
        else xh32[n] = v;
    }
}

// ---------------- layer-1 aggregate (33 feats), single-node (r13 form) ----------------
__global__ void __launch_bounds__(256) k_agg1(
    const __half* __restrict__ xh, const __half* __restrict__ xh32,
    const int* __restrict__ ptr, const unsigned* __restrict__ er,
    const float* __restrict__ ew, const float* __restrict__ ebv,
    const float* __restrict__ epsp, float* __restrict__ h) {
    int t = threadIdx.x;
    int wave = t >> 6, lane = t & 63;
    int slot = lane >> 2, q = lane & 3;
    float4 ewa = ((const float4*)ew)[q * 2];
    float4 ewb = ((const float4*)ew)[q * 2 + 1];
    float4 eba = ((const float4*)ebv)[q * 2];
    float4 ebb = ((const float4*)ebv)[q * 2 + 1];
    float ew32 = ew[32], eb32 = ebv[32];
    float ep = 1.f + epsp[0];
    for (int quad = blockIdx.x; quad < NQUAD; quad += AGBLK) {
        int node = quad * 4 + wave;
        float a[8] = {0, 0, 0, 0, 0, 0, 0, 0};
        float a32 = 0.f;
        int e0 = ptr[node], e1 = ptr[node + 1];
        for (int i = e0 + slot; i < e1; i += 16) {
            unsigned ev = er[i];
            int s = ev & 0x1FFFF;
            float wv = (float)(ev >> 17) * WDEC;
            uint4 raw = *(const uint4*)(xh + s * ROW1 + q * 8);
            float2 f01 = __half22float2(*(__half2*)&raw.x);
            float2 f23 = __half22float2(*(__half2*)&raw.y);
            float2 f45 = __half22float2(*(__half2*)&raw.z);
            float2 f67 = __half22float2(*(__half2*)&raw.w);
            a[0] += fmaxf(f01.x + wv * ewa.x + eba.x, 0.f);
            a[1] += fmaxf(f01.y + wv * ewa.y + eba.y, 0.f);
            a[2] += fmaxf(f23.x + wv * ewa.z + eba.z, 0.f);
            a[3] += fmaxf(f23.y + wv * ewa.w + eba.w, 0.f);
            a[4] += fmaxf(f45.x + wv * ewb.x + ebb.x, 0.f);
            a[5] += fmaxf(f45.y + wv * ewb.y + ebb.y, 0.f);
            a[6] += fmaxf(f67.x + wv * ewb.z + ebb.z, 0.f);
            a[7] += fmaxf(f67.y + wv * ewb.w + ebb.w, 0.f);
            if (q == 0) a32 += fmaxf(__half2float(xh32[s]) + wv * ew32 + eb32, 0.f);
        }
        #pragma unroll
        for (int m = 4; m <= 32; m <<= 1) {
            #pragma unroll
            for (int j = 0; j < 8; j++) a[j] += __shfl_xor(a[j], m);
            a32 += __shfl_xor(a32, m);
        }
        if (slot == 0) {
            uint4 sraw = *(const uint4*)(xh + node * ROW1 + q * 8);
            float2 s01 = __half22float2(*(__half2*)&sraw.x);
            float2 s23 = __half22float2(*(__half2*)&sraw.y);
            float2 s45 = __half22float2(*(__half2*)&sraw.z);
            float2 s67 = __half22float2(*(__half2*)&sraw.w);
            float* hp = h + node * H1STR + q * 8;
            *(float4*)hp = make_float4(ep * s01.x + a[0], ep * s01.y + a[1],
                                       ep * s23.x + a[2], ep * s23.y + a[3]);
            *(float4*)(hp + 4) = make_float4(ep * s45.x + a[4], ep * s45.y + a[5],
                                             ep * s67.x + a[6], ep * s67.y + a[7]);
            if (q == 0)
                h[node * H1STR + 32] = ep * __half2float(xh32[node]) + a32;
        }
    }
}

// ---------------- layer 2-5 aggregate (16 feats), BN folded, dual-node ----------------
__global__ void __launch_bounds__(256) k_agg16(
    const __half* __restrict__ zh, const int* __restrict__ ptr,
    const unsigned* __restrict__ er,
    const float* __restrict__ ew, const float* __restrict__ ebv,
    const float* __restrict__ epsp,
    const float* __restrict__ bnstat, const float* __restrict__ gamma,
    const float* __restrict__ beta, float* __restrict__ h) {
    int t = threadIdx.x;
    int wave = t >> 6, lane = t & 63;
    int slot = lane >> 1, hh = lane & 1;
    float ep = 1.f + epsp[0];
    const float invn = 1.f / (float)N_NODES;
    float scf[8], shf[8], cbf[8], ewf[8];
    #pragma unroll
    for (int j = 0; j < 8; j++) {
        int f = hh * 8 + j;
        float mu = bnstat[f] * invn;
        float var = bnstat[DIM + f] * invn - mu * mu;
        float sc = gamma[f] * rsqrtf(var + BN_EPSV);
        scf[j] = sc;
        shf[j] = beta[f] - mu * sc;
        cbf[j] = shf[j] + ebv[f];
        ewf[j] = ew[f];
    }
    for (int quad = blockIdx.x; quad < NQUAD; quad += 2 * AGBLK) {
        int quadB = quad + AGBLK;
        bool hasB = quadB < NQUAD;
        int nodeA = quad * 4 + wave;
        int nodeB = hasB ? quadB * 4 + wave : nodeA;
        float a[8] = {0, 0, 0, 0, 0, 0, 0, 0};
        float b[8] = {0, 0, 0, 0, 0, 0, 0, 0};
        int e0a = ptr[nodeA], e1a = ptr[nodeA + 1];
        int e0b = ptr[nodeB], e1b = ptr[nodeB + 1];
        if (!hasB) e1b = e0b;
        int ia = e0a + slot, ib = e0b + slot;
        while (ia < e1a || ib < e1b) {
            bool da = ia < e1a, db = ib < e1b;
            unsigned evA = 0, evB = 0;
            if (da) evA = er[ia];
            if (db) evB = er[ib];
            uint4 rA, rB;
            float wvA = 0.f, wvB = 0.f;
            if (da) {
                rA = *(const uint4*)(zh + (evA & 0x1FFFF) * DIM + hh * 8);
                wvA = (float)(evA >> 17) * WDEC;
            }
            if (db) {
                rB = *(const uint4*)(zh + (evB & 0x1FFFF) * DIM + hh * 8);
                wvB = (float)(evB >> 17) * WDEC;
            }
            if (da) {
                float2 f01 = __half22float2(*(__half2*)&rA.x);
                float2 f23 = __half22float2(*(__half2*)&rA.y);
                float2 f45 = __half22float2(*(__half2*)&rA.z);
                float2 f67 = __half22float2(*(__half2*)&rA.w);
                float x[8] = {f01.x, f01.y, f23.x, f23.y, f45.x, f45.y, f67.x, f67.y};
                #pragma unroll
                for (int j = 0; j < 8; j++) {
                    float tb = fmaf(wvA, ewf[j], cbf[j]);
                    a[j] += fmaxf(fmaf(x[j], scf[j], tb), 0.f);
                }
            }
            if (db) {
                float2 f01 = __half22float2(*(__half2*)&rB.x);
                float2 f23 = __half22float2(*(__half2*)&rB.y);
                float2 f45 = __half22float2(*(__half2*)&rB.z);
                float2 f67 = __half22float2(*(__half2*)&rB.w);
                float x[8] = {f01.x, f01.y, f23.x, f23.y, f45.x, f45.y, f67.x, f67.y};
                #pragma unroll
                for (int j = 0; j < 8; j++) {
                    float tb = fmaf(wvB, ewf[j], cbf[j]);
                    b[j] += fmaxf(fmaf(x[j], scf[j], tb), 0.f);
                }
            }
            ia += 32; ib += 32;
        }
        #pragma unroll
        for (int m = 2; m <= 32; m <<= 1) {
            #pragma unroll
            for (int j = 0; j < 8; j++) {
                a[j] += __shfl_xor(a[j], m);
                b[j] += __shfl_xor(b[j], m);
            }
        }
        if (lane < 2) {
            {
                uint4 sraw = *(const uint4*)(zh + nodeA * DIM + lane * 8);
                float2 s01 = __half22float2(*(__half2*)&sraw.x);
                float2 s23 = __half22float2(*(__half2*)&sraw.y);
                float2 s45 = __half22float2(*(__half2*)&sraw.z);
                float2 s67 = __half22float2(*(__half2*)&sraw.w);
                float xs[8] = {s01.x, s01.y, s23.x, s23.y, s45.x, s45.y, s67.x, s67.y};
                float o8[8];
                #pragma unroll
                for (int j = 0; j < 8; j++)
                    o8[j] = ep * fmaf(xs[j], scf[j], shf[j]) + a[j];
                float* hp = h + nodeA * DIM + lane * 8;
                *(float4*)hp = make_float4(o8[0], o8[1], o8[2], o8[3]);
                *(float4*)(hp + 4) = make_float4(o8[4], o8[5], o8[6], o8[7]);
            }
            if (hasB) {
                uint4 sraw = *(const uint4*)(zh + nodeB * DIM + lane * 8);
                float2 s01 = __half22float2(*(__half2*)&sraw.x);
                float2 s23 = __half22float2(*(__half2*)&sraw.y);
                float2 s45 = __half22float2(*(__half2*)&sraw.z);
                float2 s67 = __half22float2(*(__half2*)&sraw.w);
                float xs[8] = {s01.x, s01.y, s23.x, s23.y, s45.x, s45.y, s67.x, s67.y};
                float o8[8];
                #pragma unroll
                for (int j = 0; j < 8; j++)
                    o8[j] = ep * fmaf(xs[j], scf[j], shf[j]) + b[j];
                float* hp = h + nodeB * DIM + lane * 8;
                *(float4*)hp = make_float4(o8[0], o8[1], o8[2], o8[3]);
                *(float4*)(hp + 4) = make_float4(o8[4], o8[5], o8[6], o8[7]);
            }
        }
    }
}

// ---------------- fused per-thread MLP + shfl-reduced BN partials, fp16 z out ----------------
__device__ __forceinline__ void mlp_bn_tail(float zv[16], bool active, int t,
                                            float* __restrict__ part) {
    __shared__ float red[4][32];
    float zs[16], zq[16];
    #pragma unroll
    for (int o = 0; o < 16; o++) {
        zs[o] = active ? zv[o] : 0.f;
        zq[o] = active ? zv[o] * zv[o] : 0.f;
    }
    #pragma unroll
    for (int m = 1; m <= 32; m <<= 1) {
        #pragma unroll
        for (int o = 0; o < 16; o++) {
            zs[o] += __shfl_xor(zs[o], m);
            zq[o] += __shfl_xor(zq[o], m);
        }
    }
    int wave = t >> 6, lane = t & 63;
    if (lane == 0) {
        #pragma unroll
        for (int o = 0; o < 16; o++) {
            red[wave][o] = zs[o];
            red[wave][16 + o] = zq[o];
        }
    }
    __syncthreads();
    if (t < 32)
        part[blockIdx.x * 32 + t] = red[0][t] + red[1][t] + red[2][t] + red[3][t];
}

__device__ __forceinline__ void store_zh(__half* __restrict__ zh, int n, float zv[16]) {
    __half2 p[8];
    #pragma unroll
    for (int j = 0; j < 8; j++) p[j] = __floats2half2_rn(zv[2 * j], zv[2 * j + 1]);
    *(uint4*)(zh + n * DIM) = *(uint4*)&p[0];
    *(uint4*)(zh + n * DIM + 8) = *(uint4*)&p[4];
}

__global__ void __launch_bounds__(256) k_mlp16(
    const float* __restrict__ h,
    const float* __restrict__ W1, const float* __restrict__ b1,
    const float* __restrict__ W2, const float* __restrict__ b2,
    __half* __restrict__ zh, float* __restrict__ part) {
    __shared__ float W1s[256], W2s[256], b1s[16], b2s[16];
    int t = threadIdx.x;
    W1s[t] = W1[t];
    W2s[t] = W2[t];
    if (t < 16) { b1s[t] = b1[t]; b2s[t] = b2[t]; }
    __syncthreads();
    int n = blockIdx.x * 256 + t;
    bool active = n < N_NODES;
    float zv[16];
    if (active) {
        float hv[16];
        #pragma unroll
        for (int j = 0; j < 4; j++) {
            float4 v = *(const float4*)(h + n * DIM + j * 4);
            hv[j * 4] = v.x; hv[j * 4 + 1] = v.y; hv[j * 4 + 2] = v.z; hv[j * 4 + 3] = v.w;
        }
        float tv[16];
        #pragma unroll
        for (int o = 0; o < 16; o++) {
            float s = b1s[o];
            #pragma unroll
            for (int f = 0; f < 16; f++) s += hv[f] * W1s[f * 16 + o];
            tv[o] = fmaxf(s, 0.f);
        }
        #pragma unroll
        for (int o = 0; o < 16; o++) {
            float s = b2s[o];
            #pragma unroll
            for (int f = 0; f < 16; f++) s += tv[f] * W2s[f * 16 + o];
            zv[o] = fmaxf(s, 0.f);
        }
        store_zh(zh, n, zv);
    }
    mlp_bn_tail(zv, active, t, part);
}

__global__ void __launch_bounds__(256) k_mlp1(
    const float* __restrict__ h,
    const float* __restrict__ W1, const float* __restrict__ b1,
    const float* __restrict__ W2, const float* __restrict__ b2,
    __half* __restrict__ zh, float* __restrict__ part) {
    __shared__ float W1s[NFP * 16], W2s[256], b1s[16], b2s[16];
    int t = threadIdx.x;
    for (int j = t; j < NFP * 16; j += 256) W1s[j] = W1[j];
    W2s[t] = W2[t];
    if (t < 16) { b1s[t] = b1[t]; b2s[t] = b2[t]; }
    __syncthreads();
    int n = blockIdx.x * 256 + t;
    bool active = n < N_NODES;
    float zv[16];
    if (active) {
        float hv[NFP];
        #pragma unroll
        for (int j = 0; j < 8; j++) {
            float4 v = *(const float4*)(h + n * H1STR + j * 4);
            hv[j * 4] = v.x; hv[j * 4 + 1] = v.y; hv[j * 4 + 2] = v.z; hv[j * 4 + 3] = v.w;
        }
        hv[32] = h[n * H1STR + 32];
        float tv[16];
        #pragma unroll
        for (int o = 0; o < 16; o++) {
            float s = b1s[o];
            #pragma unroll
            for (int f = 0; f < NFP; f++) s += hv[f] * W1s[f * 16 + o];
            tv[o] = fmaxf(s, 0.f);
        }
        #pragma unroll
        for (int o = 0; o < 16; o++) {
            float s = b2s[o];
            #pragma unroll
            for (int f = 0; f < 16; f++) s += tv[f] * W2s[f * 16 + o];
            zv[o] = fmaxf(s, 0.f);
        }
        store_zh(zh, n, zv);
    }
    mlp_bn_tail(zv, active, t, part);
}

// ---------------- reduce block partials -> bnstat[32] ----------------
__global__ void __launch_bounds__(1024) k_bnred(const float* __restrict__ part,
                                                float* __restrict__ bnstat) {
    __shared__ float red[1024];
    int t = threadIdx.x;
    int f = t & 31, g = t >> 5;
    float s = 0.f;
    for (int i = g; i < MLPB; i += 32) s += part[i * 32 + f];
    red[t] = s;
    __syncthreads();
    for (int off = 512; off >= 32; off >>= 1) {
        if (t < off) red[t] += red[t + off];
        __syncthreads();
    }
    if (t < 32) bnstat[t] = red[t];
}

// ---------------- pooling with BN folded in ----------------
__global__ void __launch_bounds__(256) k_pool(const __half* __restrict__ zh,
                                              const int* __restrict__ batch,
                                              const float* __restrict__ bnstat,
                                              const float* __restrict__ gamma,
                                              const float* __restrict__ beta,
                                              float* __restrict__ gsum,
                                              float* __restrict__ gcnt) {
    __shared__ float lsum[BGR * DIM];
    __shared__ float lcnt[BGR];
    int t = threadIdx.x;
    for (int j = t; j < BGR * DIM; j += 256) lsum[j] = 0.f;
    if (t < BGR) lcnt[t] = 0.f;
    __syncthreads();
    int f = t & 15, r = t >> 4;
    const float invn = 1.f / (float)N_NODES;
    float mu = bnstat[f] * invn;
    float var = bnstat[DIM + f] * invn - mu * mu;
    float sc = gamma[f] * rsqrtf(var + BN_EPSV);
    float sh = beta[f] - mu * sc;
    int start = blockIdx.x * POOL_CHUNK;
    float acc = 0.f, cacc = 0.f;
    int cur = -1;
    for (int i = 0; i < POOL_CHUNK / 16; i++) {
        int n = start + r + i * 16;
        if (n >= N_NODES) break;
        int b = batch[n];
        if (b != cur) {
            if (cur >= 0) {
                atomicAdd(&lsum[cur * DIM + f], acc);
                if (f == 0) atomicAdd(&lcnt[cur], cacc);
            }
            cur = b; acc = 0.f; cacc = 0.f;
        }
        acc += fmaf(__half2float(zh[n * DIM + f]), sc, sh);
        cacc += 1.f;
    }
    if (cur >= 0) {
        atomicAdd(&lsum[cur * DIM + f], acc);
        if (f == 0) atomicAdd(&lcnt[cur], cacc);
    }
    __syncthreads();
    for (int j = t; j < BGR * DIM; j += 256) {
        float v = lsum[j];
        if (v != 0.f) atomicAdd(&gsum[j], v);
    }
    if (t < BGR) {
        float v = lcnt[t];
        if (v != 0.f) atomicAdd(&gcnt[t], v);
    }
}

__global__ void k_xp(const float* __restrict__ gsum, const float* __restrict__ gcnt,
                     const float* __restrict__ w, const float* __restrict__ bias,
                     float* __restrict__ out) {
    int b = blockIdx.x;
    int e = threadIdx.x;
    float inv = 1.f / fmaxf(gcnt[b], 1.f);
    float acc = bias[e];
    #pragma unroll
    for (int f = 0; f < DIM; f++) acc += gsum[b * DIM + f] * inv * w[f * EMB + e];
    out[b * EMB + e] = fmaxf(acc, 0.f);
}

// ---------------- RNA ----------------
__global__ void __launch_bounds__(256) k_bucket(const int* __restrict__ tok, int L, int V,
                                                int* __restrict__ blist,
                                                int* __restrict__ bptr) {
    __shared__ int hist[65];
    __shared__ int cursor[65];
    int b = blockIdx.x, t = threadIdx.x;
    if (t < V) hist[t] = 0;
    __syncthreads();
    for (int l = t; l < L; l += 256) atomicAdd(&hist[tok[b * L + l]], 1);
    __syncthreads();
    if (t == 0) {
        int run = 0;
        for (int v = 0; v < V; v++) {
            cursor[v] = run;
            bptr[b * (V + 1) + v] = run;
            run += hist[v];
        }
        bptr[b * (V + 1) + V] = run;
    }
    __syncthreads();
    for (int l = t; l < L; l += 256) {
        int v = tok[b * L + l];
        int p = atomicAdd(&cursor[v], 1);
        blist[b * L + p] = l;
    }
}

__global__ void __launch_bounds__(256) k_wsum(const int* __restrict__ blist,
                                              const int* __restrict__ bptr,
                                              const float* __restrict__ cw,
                                              float* __restrict__ W, int L, int V) {
    int b = blockIdx.x, v = blockIdx.y;
    int t = threadIdx.x, o = t >> 3, k = t & 7;
    int s = bptr[b * (V + 1) + v], e = bptr[b * (V + 1) + v + 1];
    __shared__ int tk[256];
    const float* cwp = cw + o * (L * KS) + k;
    float acc = 0.f;
    for (int j0 = s; j0 < e; j0 += 256) {
        int lim = e - j0; if (lim > 256) lim = 256;
        __syncthreads();
        if (t < lim) tk[t] = blist[b * L + j0 + t];
        __syncthreads();
        for (int j = 0; j < lim; j++) acc += cwp[tk[j] * KS];
    }
    W[((b * NF + o) * V + v) * KS + k] = acc;
}

__global__ void k_y(const float* __restrict__ Wg, const float* __restrict__ Wl,
                    const float* __restrict__ emb1, const float* __restrict__ emb2,
                    const float* __restrict__ cb1, const float* __restrict__ cb2,
                    float* __restrict__ yg, float* __restrict__ yl) {
    int which = blockIdx.y;
    int bo = blockIdx.x;
    int b = bo >> 5, o = bo & 31;
    int t = threadIdx.x;  // 128
    const float* W = which ? Wl : Wg;
    const float* emb = which ? emb2 : emb1;
    const float* cb = which ? cb2 : cb1;
    float* y = which ? yl : yg;
    int V = which ? 65 : 5;
    __shared__ float Wsh[65 * KS];
    const float* Wrow = W + (b * NF + o) * V * KS;
    for (int j = t; j < V * KS; j += 128) Wsh[j] = Wrow[j];
    __syncthreads();
    if (t < OUTT) {
        float acc = cb[o];
        for (int v = 0; v < V; v++) {
            const float* ep = emb + v * EMB + t;
            #pragma unroll
            for (int k = 0; k < KS; k++) acc += Wsh[v * KS + k] * ep[k];
        }
        y[(b * NF + o) * OUTT + t] = acc;
    }
}

__global__ void __launch_bounds__(128) k_fcpart(const float* __restrict__ yg,
                                                const float* __restrict__ yl,
                                                const float* __restrict__ w,
                                                float* __restrict__ partial) {
    int b = blockIdx.x, which = blockIdx.y, kc = blockIdx.z;
    const float* y = which ? yl : yg;
    int e = threadIdx.x;
    __shared__ float ych[KCH];
    int j0 = kc * KCH;
    if (e < KCH) ych[e] = y[b * FC_IN + j0 + e];
    __syncthreads();
    float acc = 0.f;
    #pragma unroll 4
    for (int jj = 0; jj < KCH; jj++) acc += ych[jj] * w[(j0 + jj) * EMB + e];
    partial[((which * BGR + b) * NKC + kc) * EMB + e] = acc;
}

__global__ void k_fcred(const float* __restrict__ partial, const float* __restrict__ bias,
                        float* __restrict__ out) {
    int b = blockIdx.x;
    int e = threadIdx.x;
    const float* pg = partial + b * NKC * EMB + e;
    const float* pl = partial + (BGR + b) * NKC * EMB + e;
    float ag = bias[e], al = bias[e];
    #pragma unroll
    for (int k = 0; k < NKC; k++) { ag += pg[k * EMB]; al += pl[k * EMB]; }
    out[b * EMB + e] = 0.5f * (ag + al);
}

extern "C" void kernel_launch(void* const* d_in, const int* in_sizes, int n_in,
                              void* d_out, int out_size, void* d_ws, size_t ws_size,
                              hipStream_t stream) {
    const float* pro_x = (const float*)d_in[0];
    const int* eidx = (const int*)d_in[1];
    const int* esrc = eidx;
    const int* edst = eidx + N_EDGES;
    const float* pw = (const float*)d_in[2];
    const int* batch = (const int*)d_in[3];
    const int* rg = (const int*)d_in[4];
    const int* rl = (const int*)d_in[5];
    const float* g1_w1 = (const float*)d_in[6];
    const float* g1_b1 = (const float*)d_in[7];
    const float* g1_w2 = (const float*)d_in[8];
    const float* g1_b2 = (const float*)d_in[9];
    const float* g1_ew = (const float*)d_in[10];
    const float* g1_eb = (const float*)d_in[11];
    const float* g1_eps = (const float*)d_in[12];
    const float* g_w1 = (const float*)d_in[13];
    const float* g_b1 = (const float*)d_in[14];
    const float* g_w2 = (const float*)d_in[15];
    const float* g_b2 = (const float*)d_in[16];
    const float* g_ew = (const float*)d_in[17];
    const float* g_eb = (const float*)d_in[18];
    const float* g_eps = (const float*)d_in[19];
    const float* bn_gamma = (const float*)d_in[20];
    const float* bn_beta = (const float*)d_in[21];
    const float* fc1_xp_w = (const float*)d_in[22];
    const float* fc1_xp_b = (const float*)d_in[23];
    const float* emb1 = (const float*)d_in[24];
    const float* emb2 = (const float*)d_in[25];
    const float* convr1_w = (const float*)d_in[26];
    const float* convr1_b = (const float*)d_in[27];
    const float* convr2_w = (const float*)d_in[28];
    const float* convr2_b = (const float*)d_in[29];
    const float* fcxr_w = (const float*)d_in[30];
    const float* fcxr_b = (const float*)d_in[31];
    float* out = (float*)d_out;

    // persistent buffers
    float* wsf = (float*)d_ws;
    int* ptr       = (int*)wsf;        wsf += 100128;
    int* binoff    = (int*)wsf;        wsf += 512;
    int* bincur    = (int*)wsf;        wsf += 512;
    unsigned* er   = (unsigned*)wsf;   wsf += 2 * N_EDGES;  // only N_EDGES used (4B records)
    float* stats   = wsf;              wsf += 1280;
    // union region
    float* un = wsf;
    int2* tmp_sw          = (int2*)un;
    int* bh               = (int*)(un + 7200000);
    __half* zh   = (__half*)(un + 1600000);
    __half* xh1  = (__half*)(un + 2400000);
    __half* xh32 = (__half*)(un + 4000000);
    float* bpart = un + 4100000;
    float* Wg    = un + 4300000;
    float* Wl    = un + 4382000;
    float* yg    = un + 5447000;
    float* yl    = un + 5695000;
    int* blg     = (int*)(un + 5961000);
    int* bll     = (int*)(un + 6153000);
    int* bpg     = (int*)(un + 6345000);
    int* bpl     = (int*)(un + 6346000);
    float* fcpart = un + 6360000;
    float* h      = un + 7400000;
    float* gsum   = stats;
    float* gcnt   = stats + 1024;
    float* bnstat = stats + 1088;

    hipMemsetAsync(stats, 0, 1280 * sizeof(float), stream);

    // CSR build
    k_bincnt<<<BCNT_BLK, 256, 0, stream>>>(edst, bh);
    k_binscan<<<1, 512, 0, stream>>>(bh, binoff, bincur);
    k_part1<<<P1_BLOCKS, 256, 0, stream>>>(esrc, edst, pw, bincur, tmp_sw);
    k_part2<<<NBIN, 256, 0, stream>>>(tmp_sw, binoff, er, ptr);

    // pro_x -> fp16 rows
    k_half1<<<(N_NODES * NFP + 255) / 256, 256, 0, stream>>>(pro_x, xh1, xh32);

    // RNA branch
    k_bucket<<<BGR, 256, 0, stream>>>(rg, MAXLEN, 5, blg, bpg);
    k_bucket<<<BGR, 256, 0, stream>>>(rl, LOCLEN, 65, bll, bpl);
    k_wsum<<<dim3(BGR, 5), 256, 0, stream>>>(blg, bpg, convr1_w, Wg, MAXLEN, 5);
    k_wsum<<<dim3(BGR, 65), 256, 0, stream>>>(bll, bpl, convr2_w, Wl, LOCLEN, 65);
    k_y<<<dim3(BGR * NF, 2), 128, 0, stream>>>(Wg, Wl, emb1, emb2, convr1_b, convr2_b, yg, yl);
    k_fcpart<<<dim3(BGR, 2, NKC), 128, 0, stream>>>(yg, yl, fcxr_w, fcpart);
    k_fcred<<<BGR, 128, 0, stream>>>(fcpart, fcxr_b, out);

    // GNN stack
    k_agg1<<<AGBLK, 256, 0, stream>>>(xh1, xh32, ptr, er, g1_ew, g1_eb, g1_eps, h);
    k_mlp1<<<MLPB, 256, 0, stream>>>(h, g1_w1, g1_b1, g1_w2, g1_b2, zh, bpart);
    k_bnred<<<1, 1024, 0, stream>>>(bpart, bnstat);
    for (int i = 0; i < 4; i++) {
        k_agg16<<<AGBLK, 256, 0, stream>>>(zh, ptr, er,
                                           g_ew + i * DIM, g_eb + i * DIM, g_eps + i,
                                           bnstat + i * 32, bn_gamma + i * DIM,
                                           bn_beta + i * DIM, h);
        k_mlp16<<<MLPB, 256, 0, stream>>>(h, g_w1 + i * DIM * DIM, g_b1 + i * DIM,
                                          g_w2 + i * DIM * DIM, g_b2 + i * DIM, zh, bpart);
        k_bnred<<<1, 1024, 0, stream>>>(bpart, bnstat + (i + 1) * 32);
    }
    k_pool<<<POOL_BLKS, 256, 0, stream>>>(zh, batch, bnstat + 4 * 32,
                                          bn_gamma + 4 * DIM, bn_beta + 4 * DIM, gsum, gcnt);
    k_xp<<<BGR, EMB, 0, stream>>>(gsum, gcnt, fc1_xp_w, fc1_xp_b, out + BGR * EMB);
}